// Round 10
// baseline (352.478 us; speedup 1.0000x reference)
//
#include <hip/hip_runtime.h>

#define N_NODES 50000
#define N_EDGES 800000
#define DIM 128
#define NB 196          // buckets of 256 nodes
#define CHUNK 4096      // edges per chunk; 196*4096 >= 800000
#define GRID 196        // chunks == buckets == blocks for build passes
#define SEG_CAP 6144    // LDS csr segment cap (mean 4096, sigma 64)
#define NCH 4           // channel chunks: 128/4 = 32 ch = 64 B rows, 3.2 MB slab

// ---------------- bf16 pack/unpack (RNE) ----------------

__device__ inline unsigned pk_bf16(float a, float b) {
    unsigned ua = __float_as_uint(a); ua = (ua + 0x7FFFu + ((ua >> 16) & 1u)) >> 16;
    unsigned ub = __float_as_uint(b); ub = (ub + 0x7FFFu + ((ub >> 16) & 1u)) >> 16;
    return ua | (ub << 16);
}
__device__ inline float bf_lo(unsigned u) { return __uint_as_float(u << 16); }
__device__ inline float bf_hi(unsigned u) { return __uint_as_float(u & 0xFFFF0000u); }

// ---------------- Pass A: per-chunk bucket histogram -> chist[bid][*] ------

__global__ __launch_bounds__(256) void chunk_hist(const int* __restrict__ dst,
                                                  int* __restrict__ chist) {
    __shared__ int hist[256];
    const int t = threadIdx.x;
    const int eb = blockIdx.x * CHUNK;
    const int cnt = min(CHUNK, N_EDGES - eb);
    hist[t] = 0;
    __syncthreads();
    for (int i = t; i < cnt; i += 256)
        atomicAdd(&hist[dst[eb + i] >> 8], 1);
    __syncthreads();
    chist[blockIdx.x * 256 + t] = hist[t];
}

// ---------------- Pass B: counting sort; offsets derived from chist --------

__global__ __launch_bounds__(256) void sort_scatter(const int* __restrict__ src,
                                                    const int* __restrict__ dst,
                                                    const int* __restrict__ chist,
                                                    unsigned* __restrict__ sorted) {
    __shared__ int hist[256], sc[256], lbase[256], lcur[256], gbase[256];
    __shared__ unsigned sl[CHUNK];
    const int t = threadIdx.x;
    const int bid = blockIdx.x;
    const int eb = bid * CHUNK;
    const int cnt = min(CHUNK, N_EDGES - eb);

    int sum = 0, myoff = 0;
    for (int c = 0; c < GRID; ++c) {
        int v = chist[c * 256 + t];
        if (c == bid) myoff = sum;
        sum += v;
    }
    hist[t] = chist[bid * 256 + t];
    sc[t] = sum;
    __syncthreads();
    for (int off = 1; off < 256; off <<= 1) {
        int u = (t >= off) ? sc[t - off] : 0;
        __syncthreads();
        sc[t] += u;
        __syncthreads();
    }
    gbase[t] = (sc[t] - sum) + myoff;
    __syncthreads();

    sc[t] = hist[t];
    __syncthreads();
    for (int off = 1; off < 256; off <<= 1) {
        int u = (t >= off) ? sc[t - off] : 0;
        __syncthreads();
        sc[t] += u;
        __syncthreads();
    }
    int ex = sc[t] - hist[t];
    lbase[t] = ex;
    lcur[t] = ex;
    __syncthreads();

    for (int i = t; i < cnt; i += 256) {
        int s = src[eb + i], d = dst[eb + i];
        int b = d >> 8;
        int p = atomicAdd(&lcur[b], 1);
        sl[p] = ((unsigned)b << 24) | ((unsigned)(d & 255) << 16) | (unsigned)s;
    }
    __syncthreads();
    for (int i = t; i < cnt; i += 256) {
        unsigned rec = sl[i];
        int b = rec >> 24;
        sorted[gbase[b] + (i - lbase[b])] = rec;
    }
}

// ---------------- Pass C: per-bucket CSR finalize (block = bucket) ----------

__global__ __launch_bounds__(256) void csr_build(const unsigned* __restrict__ sorted,
                                                 const int* __restrict__ chist,
                                                 int* __restrict__ rowptr,
                                                 float* __restrict__ dinv,
                                                 int* __restrict__ csr) {
    __shared__ int hist[256], sc[256], lcur[256], bbase_s[256], cnt_s[256];
    __shared__ int seg[SEG_CAP];
    const int t = threadIdx.x;
    const int k = blockIdx.x;

    int sum = 0;
    for (int c = 0; c < GRID; ++c) sum += chist[c * 256 + t];
    cnt_s[t] = sum;
    sc[t] = sum;
    __syncthreads();
    for (int off = 1; off < 256; off <<= 1) {
        int u = (t >= off) ? sc[t - off] : 0;
        __syncthreads();
        sc[t] += u;
        __syncthreads();
    }
    bbase_s[t] = sc[t] - cnt_s[t];
    __syncthreads();
    const int base = bbase_s[k];
    const int cntk = cnt_s[k];
    if (k == 0 && t == 0) rowptr[N_NODES] = N_EDGES;

    hist[t] = 0;
    __syncthreads();
    for (int i = t; i < cntk; i += 256)
        atomicAdd(&hist[(sorted[base + i] >> 16) & 255], 1);
    __syncthreads();

    const int node = (k << 8) + t;
    const int dv = hist[t];
    if (node < N_NODES) dinv[node] = rsqrtf((float)dv + 1.0f);   // +1 self-loop

    sc[t] = dv;
    __syncthreads();
    for (int off = 1; off < 256; off <<= 1) {
        int u = (t >= off) ? sc[t - off] : 0;
        __syncthreads();
        sc[t] += u;
        __syncthreads();
    }
    int ex = sc[t] - dv;
    if (node < N_NODES) rowptr[node] = base + ex;
    lcur[t] = ex;
    __syncthreads();

    if (cntk <= SEG_CAP) {
        for (int i = t; i < cntk; i += 256) {
            unsigned rec = sorted[base + i];
            int p = atomicAdd(&lcur[(rec >> 16) & 255], 1);
            seg[p] = (int)(rec & 0xFFFFu);
        }
        __syncthreads();
        for (int i = t; i < cntk; i += 256)
            csr[base + i] = seg[i];
    } else {
        for (int i = t; i < cntk; i += 256) {
            unsigned rec = sorted[base + i];
            int p = atomicAdd(&lcur[(rec >> 16) & 255], 1);
            csr[base + p] = (int)(rec & 0xFFFFu);
        }
    }
}

// ---- GEMM: hp = (X @ W) * dinv, written CHUNK-MAJOR bf16:
//      hp[c][node][8 uint2]  (c = channel chunk of 32, 64 B rows) ----

__global__ __launch_bounds__(256) void gemm_xw(const float* __restrict__ X,
                                               const float* __restrict__ W,
                                               const float* __restrict__ dinv,
                                               uint2* __restrict__ O, int nrows) {
    __shared__ float Xs[64][128];
    const int rbase = blockIdx.x * 64;
    const int t = threadIdx.x;

    for (int idx = t; idx < 2048; idx += 256) {
        int r = idx >> 5;
        int gr = rbase + r;
        float4 v = make_float4(0.f, 0.f, 0.f, 0.f);
        if (gr < nrows) v = ((const float4*)X)[(size_t)gr * 32 + (idx & 31)];
        ((float4*)Xs)[idx] = v;
    }
    __syncthreads();

    const int ct = t & 31;        // float4 col group: channels [ct*4, ct*4+4)
    const int rt = t >> 5;
    float4 acc[8];
#pragma unroll
    for (int j = 0; j < 8; ++j) acc[j] = make_float4(0.f, 0.f, 0.f, 0.f);

    const float4* W4 = (const float4*)W;
    for (int k0 = 0; k0 < 128; k0 += 4) {
        float4 xk[8];
#pragma unroll
        for (int j = 0; j < 8; ++j)
            xk[j] = *(const float4*)&Xs[rt * 8 + j][k0];
#pragma unroll
        for (int kk = 0; kk < 4; ++kk) {
            float4 w = W4[(k0 + kk) * 32 + ct];
#pragma unroll
            for (int j = 0; j < 8; ++j) {
                float xv = (kk == 0) ? xk[j].x : (kk == 1) ? xk[j].y
                          : (kk == 2) ? xk[j].z : xk[j].w;
                acc[j].x += xv * w.x;
                acc[j].y += xv * w.y;
                acc[j].z += xv * w.z;
                acc[j].w += xv * w.w;
            }
        }
    }

    const int cch  = ct >> 3;     // channel chunk 0..3
    const int col8 = ct & 7;      // uint2 column within chunk
#pragma unroll
    for (int j = 0; j < 8; ++j) {
        int r = rbase + rt * 8 + j;
        if (r < nrows) {
            float di = dinv[r];
            uint2 o;
            o.x = pk_bf16(acc[j].x * di, acc[j].y * di);
            o.y = pk_bf16(acc[j].z * di, acc[j].w * di);
            O[((size_t)cch * N_NODES + r) * 8 + col8] = o;
        }
    }
}

// ---- CSR aggregate, channel-chunked: blockIdx.y = chunk (L2-resident slab).
// One wave per node; lane = (e8, col8): 8 edges x 8 uint2 per load round.

__global__ __launch_bounds__(256) void aggregate_kernel(const uint2* __restrict__ H,
                                                        const int* __restrict__ rowptr,
                                                        const int* __restrict__ csr,
                                                        const float* __restrict__ dinv,
                                                        const float4* __restrict__ b4,
                                                        float4* __restrict__ out,
                                                        int relu) {
    const int node = blockIdx.x * 4 + (threadIdx.x >> 6);
    if (node >= N_NODES) return;
    const int c    = blockIdx.y;          // channel chunk
    const int lane = threadIdx.x & 63;
    const int e8   = lane >> 3;           // edge slot 0..7
    const int col8 = lane & 7;            // uint2 column 0..7

    const uint2* Hc = H + (size_t)c * N_NODES * 8;

    float4 acc = make_float4(0.f, 0.f, 0.f, 0.f);
    if (e8 == 0) {                        // self-loop term
        uint2 v = Hc[(size_t)node * 8 + col8];
        acc.x = bf_lo(v.x); acc.y = bf_hi(v.x);
        acc.z = bf_lo(v.y); acc.w = bf_hi(v.y);
    }

    int j = rowptr[node];
    const int end = rowptr[node + 1];

#define ACCUM(v) do { \
        acc.x += bf_lo((v).x); acc.y += bf_hi((v).x); \
        acc.z += bf_lo((v).y); acc.w += bf_hi((v).y); } while (0)

    for (; j + 16 <= end; j += 16) {      // 16 edges: 2 gathers in flight
        int s0 = __builtin_nontemporal_load(&csr[j + e8]);
        int s1 = __builtin_nontemporal_load(&csr[j + 8 + e8]);
        uint2 v0 = Hc[(size_t)s0 * 8 + col8];
        uint2 v1 = Hc[(size_t)s1 * 8 + col8];
        ACCUM(v0); ACCUM(v1);
    }
    if (j + 8 <= end) {
        int s = __builtin_nontemporal_load(&csr[j + e8]);
        uint2 v = Hc[(size_t)s * 8 + col8];
        ACCUM(v);
        j += 8;
    }
    if (j + e8 < end) {                   // predicated tail (<8 edges)
        int s = __builtin_nontemporal_load(&csr[j + e8]);
        uint2 v = Hc[(size_t)s * 8 + col8];
        ACCUM(v);
    }
#undef ACCUM

    // reduce across the 8 edge slots (lanes with equal col8, stride 8)
#pragma unroll
    for (int m = 8; m <= 32; m <<= 1) {
        acc.x += __shfl_xor(acc.x, m, 64);
        acc.y += __shfl_xor(acc.y, m, 64);
        acc.z += __shfl_xor(acc.z, m, 64);
        acc.w += __shfl_xor(acc.w, m, 64);
    }

    if (e8 == 0) {
        float di = dinv[node];
        float4 bb = b4[c * 8 + col8];
        float4 o;
        o.x = acc.x * di + bb.x;
        o.y = acc.y * di + bb.y;
        o.z = acc.z * di + bb.z;
        o.w = acc.w * di + bb.w;
        if (relu) {
            o.x = fmaxf(o.x, 0.f); o.y = fmaxf(o.y, 0.f);
            o.z = fmaxf(o.z, 0.f); o.w = fmaxf(o.w, 0.f);
        }
        out[(size_t)node * 32 + c * 8 + col8] = o;   // node-major fp32 output
    }
}

// ---------------- launch ----------------

extern "C" void kernel_launch(void* const* d_in, const int* in_sizes, int n_in,
                              void* d_out, int out_size, void* d_ws, size_t ws_size,
                              hipStream_t stream) {
    const float* x  = (const float*)d_in[0];
    const int*   ei = (const int*)d_in[1];
    const float* W1 = (const float*)d_in[2];
    const float* b1 = (const float*)d_in[3];
    const float* W2 = (const float*)d_in[4];
    const float* b2 = (const float*)d_in[5];
    float* out = (float*)d_out;

    const int* src = ei;             // edge_index[0]
    const int* dst = ei + N_EDGES;   // edge_index[1]

    char* p = (char*)d_ws;
    int*      chist  = (int*)p;              p += GRID * 256 * 4;              // 200 KB
    float*    dinv   = (float*)p;            p += ((N_NODES * 4 + 1023) & ~1023);
    int*      rowptr = (int*)p;              p += (((N_NODES + 1) * 4 + 1023) & ~1023);
    unsigned* sorted = (unsigned*)p;         p += ((N_EDGES * 4 + 1023) & ~1023);
    int*      csr    = (int*)p;              p += ((N_EDGES * 4 + 1023) & ~1023);
    uint2*    hp     = (uint2*)p;            p += (size_t)N_NODES * DIM * 2;   // bf16, chunk-major
    float*    bufB   = (float*)p;                                              // fp32 h1

    const int gemmBlocks = (N_NODES + 63) / 64;   // 782
    const dim3 aggGrid((N_NODES + 3) / 4, NCH);   // y = channel chunk

    // ---- bucketed CSR build: 3 dispatches, zero global atomics, no memset ----
    chunk_hist<<<GRID, 256, 0, stream>>>(dst, chist);
    sort_scatter<<<GRID, 256, 0, stream>>>(src, dst, chist, sorted);
    csr_build<<<GRID, 256, 0, stream>>>(sorted, chist, rowptr, dinv, csr);

    // ---- layer 1: hp(bf16, chunked) = (x@W1)*dinv ; aggregate -> bufB(fp32) ----
    gemm_xw<<<gemmBlocks, 256, 0, stream>>>(x, W1, dinv, hp, N_NODES);
    aggregate_kernel<<<aggGrid, 256, 0, stream>>>(hp, rowptr, csr, dinv,
                                                  (const float4*)b1, (float4*)bufB, 1);

    // ---- layer 2: hp = (h1@W2)*dinv ; aggregate -> out ----
    gemm_xw<<<gemmBlocks, 256, 0, stream>>>(bufB, W2, dinv, hp, N_NODES);
    aggregate_kernel<<<aggGrid, 256, 0, stream>>>(hp, rowptr, csr, dinv,
                                                  (const float4*)b2, (float4*)out, 0);
}

// Round 11
// 248.510 us; speedup vs baseline: 1.4184x; 1.4184x over previous
//
#include <hip/hip_runtime.h>

#define N_NODES 50000
#define N_EDGES 800000
#define DIM 128
#define NB 196          // buckets of 256 nodes
#define CHUNK 4096      // edges per chunk; 196*4096 >= 800000
#define GRID 196        // chunks == buckets == blocks for build passes
#define SEG_CAP 6144    // LDS csr segment cap (mean 4096, sigma 64)

// ---------------- bf16 pack/unpack (RNE) ----------------

__device__ inline unsigned pk_bf16(float a, float b) {
    unsigned ua = __float_as_uint(a); ua = (ua + 0x7FFFu + ((ua >> 16) & 1u)) >> 16;
    unsigned ub = __float_as_uint(b); ub = (ub + 0x7FFFu + ((ub >> 16) & 1u)) >> 16;
    return ua | (ub << 16);
}
__device__ inline float bf_lo(unsigned u) { return __uint_as_float(u << 16); }
__device__ inline float bf_hi(unsigned u) { return __uint_as_float(u & 0xFFFF0000u); }

// ---------------- Pass A: per-chunk bucket histogram -> chist[bid][*] ------

__global__ __launch_bounds__(256) void chunk_hist(const int* __restrict__ dst,
                                                  int* __restrict__ chist) {
    __shared__ int hist[256];
    const int t = threadIdx.x;
    const int eb = blockIdx.x * CHUNK;
    const int cnt = min(CHUNK, N_EDGES - eb);
    hist[t] = 0;
    __syncthreads();
    for (int i = t; i < cnt; i += 256)
        atomicAdd(&hist[dst[eb + i] >> 8], 1);
    __syncthreads();
    chist[blockIdx.x * 256 + t] = hist[t];
}

// ---------------- Pass B: counting sort; offsets derived from chist --------
// Deterministic, zero global atomics: run offset of chunk b in bucket k =
// bucket_base(k) + sum_{c<b} chist[c][k].

__global__ __launch_bounds__(256) void sort_scatter(const int* __restrict__ src,
                                                    const int* __restrict__ dst,
                                                    const int* __restrict__ chist,
                                                    unsigned* __restrict__ sorted) {
    __shared__ int hist[256], sc[256], lbase[256], lcur[256], gbase[256];
    __shared__ unsigned sl[CHUNK];
    const int t = threadIdx.x;
    const int bid = blockIdx.x;
    const int eb = bid * CHUNK;
    const int cnt = min(CHUNK, N_EDGES - eb);

    int sum = 0, myoff = 0;
    for (int c = 0; c < GRID; ++c) {
        int v = chist[c * 256 + t];
        if (c == bid) myoff = sum;
        sum += v;
    }
    hist[t] = chist[bid * 256 + t];
    sc[t] = sum;
    __syncthreads();
    for (int off = 1; off < 256; off <<= 1) {
        int u = (t >= off) ? sc[t - off] : 0;
        __syncthreads();
        sc[t] += u;
        __syncthreads();
    }
    gbase[t] = (sc[t] - sum) + myoff;
    __syncthreads();

    sc[t] = hist[t];
    __syncthreads();
    for (int off = 1; off < 256; off <<= 1) {
        int u = (t >= off) ? sc[t - off] : 0;
        __syncthreads();
        sc[t] += u;
        __syncthreads();
    }
    int ex = sc[t] - hist[t];
    lbase[t] = ex;
    lcur[t] = ex;
    __syncthreads();

    for (int i = t; i < cnt; i += 256) {
        int s = src[eb + i], d = dst[eb + i];
        int b = d >> 8;
        int p = atomicAdd(&lcur[b], 1);
        sl[p] = ((unsigned)b << 24) | ((unsigned)(d & 255) << 16) | (unsigned)s;
    }
    __syncthreads();
    for (int i = t; i < cnt; i += 256) {
        unsigned rec = sl[i];
        int b = rec >> 24;
        sorted[gbase[b] + (i - lbase[b])] = rec;
    }
}

// ---------------- Pass C: per-bucket CSR finalize (block = bucket) ----------

__global__ __launch_bounds__(256) void csr_build(const unsigned* __restrict__ sorted,
                                                 const int* __restrict__ chist,
                                                 int* __restrict__ rowptr,
                                                 float* __restrict__ dinv,
                                                 int* __restrict__ csr) {
    __shared__ int hist[256], sc[256], lcur[256], bbase_s[256], cnt_s[256];
    __shared__ int seg[SEG_CAP];
    const int t = threadIdx.x;
    const int k = blockIdx.x;

    int sum = 0;
    for (int c = 0; c < GRID; ++c) sum += chist[c * 256 + t];
    cnt_s[t] = sum;
    sc[t] = sum;
    __syncthreads();
    for (int off = 1; off < 256; off <<= 1) {
        int u = (t >= off) ? sc[t - off] : 0;
        __syncthreads();
        sc[t] += u;
        __syncthreads();
    }
    bbase_s[t] = sc[t] - cnt_s[t];
    __syncthreads();
    const int base = bbase_s[k];
    const int cntk = cnt_s[k];
    if (k == 0 && t == 0) rowptr[N_NODES] = N_EDGES;

    hist[t] = 0;
    __syncthreads();
    for (int i = t; i < cntk; i += 256)
        atomicAdd(&hist[(sorted[base + i] >> 16) & 255], 1);
    __syncthreads();

    const int node = (k << 8) + t;
    const int dv = hist[t];
    if (node < N_NODES) dinv[node] = rsqrtf((float)dv + 1.0f);   // +1 self-loop

    sc[t] = dv;
    __syncthreads();
    for (int off = 1; off < 256; off <<= 1) {
        int u = (t >= off) ? sc[t - off] : 0;
        __syncthreads();
        sc[t] += u;
        __syncthreads();
    }
    int ex = sc[t] - dv;
    if (node < N_NODES) rowptr[node] = base + ex;
    lcur[t] = ex;
    __syncthreads();

    if (cntk <= SEG_CAP) {
        for (int i = t; i < cntk; i += 256) {
            unsigned rec = sorted[base + i];
            int p = atomicAdd(&lcur[(rec >> 16) & 255], 1);
            seg[p] = (int)(rec & 0xFFFFu);
        }
        __syncthreads();
        for (int i = t; i < cntk; i += 256)
            csr[base + i] = seg[i];
    } else {
        for (int i = t; i < cntk; i += 256) {
            unsigned rec = sorted[base + i];
            int p = atomicAdd(&lcur[(rec >> 16) & 255], 1);
            csr[base + p] = (int)(rec & 0xFFFFu);
        }
    }
}

// ---------------- GEMM (fp32 X): hp(bf16) = (X @ W) * dinv ----------------

__global__ __launch_bounds__(256) void gemm_xw(const float* __restrict__ X,
                                               const float* __restrict__ W,
                                               const float* __restrict__ dinv,
                                               uint2* __restrict__ O, int nrows) {
    __shared__ float Xs[64][128];
    const int rbase = blockIdx.x * 64;
    const int t = threadIdx.x;

    for (int idx = t; idx < 2048; idx += 256) {
        int r = idx >> 5;
        int gr = rbase + r;
        float4 v = make_float4(0.f, 0.f, 0.f, 0.f);
        if (gr < nrows) v = ((const float4*)X)[(size_t)gr * 32 + (idx & 31)];
        ((float4*)Xs)[idx] = v;
    }
    __syncthreads();

    const int ct = t & 31;
    const int rt = t >> 5;
    float4 acc[8];
#pragma unroll
    for (int j = 0; j < 8; ++j) acc[j] = make_float4(0.f, 0.f, 0.f, 0.f);

    const float4* W4 = (const float4*)W;
    for (int k0 = 0; k0 < 128; k0 += 4) {
        float4 xk[8];
#pragma unroll
        for (int j = 0; j < 8; ++j)
            xk[j] = *(const float4*)&Xs[rt * 8 + j][k0];
#pragma unroll
        for (int kk = 0; kk < 4; ++kk) {
            float4 w = W4[(k0 + kk) * 32 + ct];
#pragma unroll
            for (int j = 0; j < 8; ++j) {
                float xv = (kk == 0) ? xk[j].x : (kk == 1) ? xk[j].y
                          : (kk == 2) ? xk[j].z : xk[j].w;
                acc[j].x += xv * w.x;
                acc[j].y += xv * w.y;
                acc[j].z += xv * w.z;
                acc[j].w += xv * w.w;
            }
        }
    }

#pragma unroll
    for (int j = 0; j < 8; ++j) {
        int r = rbase + rt * 8 + j;
        if (r < nrows) {
            float di = dinv[r];
            uint2 o;
            o.x = pk_bf16(acc[j].x * di, acc[j].y * di);
            o.y = pk_bf16(acc[j].z * di, acc[j].w * di);
            O[(size_t)r * 32 + ct] = o;
        }
    }
}

// ---------------- GEMM (bf16 X): identical, staging unpacks uint2 ----------

__global__ __launch_bounds__(256) void gemm_xw_b(const uint2* __restrict__ Xb,
                                                 const float* __restrict__ W,
                                                 const float* __restrict__ dinv,
                                                 uint2* __restrict__ O, int nrows) {
    __shared__ float Xs[64][128];
    const int rbase = blockIdx.x * 64;
    const int t = threadIdx.x;

    for (int idx = t; idx < 2048; idx += 256) {          // 2048 uint2 = 64x32
        int r = idx >> 5;
        int gr = rbase + r;
        float4 f = make_float4(0.f, 0.f, 0.f, 0.f);
        if (gr < nrows) {
            uint2 v = Xb[(size_t)gr * 32 + (idx & 31)];
            f.x = bf_lo(v.x); f.y = bf_hi(v.x);
            f.z = bf_lo(v.y); f.w = bf_hi(v.y);
        }
        ((float4*)Xs)[idx] = f;
    }
    __syncthreads();

    const int ct = t & 31;
    const int rt = t >> 5;
    float4 acc[8];
#pragma unroll
    for (int j = 0; j < 8; ++j) acc[j] = make_float4(0.f, 0.f, 0.f, 0.f);

    const float4* W4 = (const float4*)W;
    for (int k0 = 0; k0 < 128; k0 += 4) {
        float4 xk[8];
#pragma unroll
        for (int j = 0; j < 8; ++j)
            xk[j] = *(const float4*)&Xs[rt * 8 + j][k0];
#pragma unroll
        for (int kk = 0; kk < 4; ++kk) {
            float4 w = W4[(k0 + kk) * 32 + ct];
#pragma unroll
            for (int j = 0; j < 8; ++j) {
                float xv = (kk == 0) ? xk[j].x : (kk == 1) ? xk[j].y
                          : (kk == 2) ? xk[j].z : xk[j].w;
                acc[j].x += xv * w.x;
                acc[j].y += xv * w.y;
                acc[j].z += xv * w.z;
                acc[j].w += xv * w.w;
            }
        }
    }

#pragma unroll
    for (int j = 0; j < 8; ++j) {
        int r = rbase + rt * 8 + j;
        if (r < nrows) {
            float di = dinv[r];
            uint2 o;
            o.x = pk_bf16(acc[j].x * di, acc[j].y * di);
            o.y = pk_bf16(acc[j].z * di, acc[j].w * di);
            O[(size_t)r * 32 + ct] = o;
        }
    }
}

// ---------------- CSR aggregate (bf16 gather; fp32 or bf16 output) ---------

__global__ __launch_bounds__(256) void aggregate_kernel(const uint2* __restrict__ H2,
                                                        const int* __restrict__ rowptr,
                                                        const int* __restrict__ csr,
                                                        const float* __restrict__ dinv,
                                                        const float4* __restrict__ b4,
                                                        void* __restrict__ outp,
                                                        int relu, int obf16) {
    int node = blockIdx.x * 4 + (threadIdx.x >> 6);
    if (node >= N_NODES) return;
    const int lane = threadIdx.x & 63;
    const int half = lane >> 5;
    const int col  = lane & 31;

    float4 acc = make_float4(0.f, 0.f, 0.f, 0.f);
    if (half == 0) {                      // self-loop term
        uint2 v = H2[(size_t)node * 32 + col];
        acc.x = bf_lo(v.x); acc.y = bf_hi(v.x);
        acc.z = bf_lo(v.y); acc.w = bf_hi(v.y);
    }

    int j = rowptr[node];
    const int end = rowptr[node + 1];

#define ACCUM(v) do { \
        acc.x += bf_lo((v).x); acc.y += bf_hi((v).x); \
        acc.z += bf_lo((v).y); acc.w += bf_hi((v).y); } while (0)

    for (; j + 16 <= end; j += 16) {
        int s0 = csr[j +  0 + half], s1 = csr[j +  2 + half];
        int s2 = csr[j +  4 + half], s3 = csr[j +  6 + half];
        int s4 = csr[j +  8 + half], s5 = csr[j + 10 + half];
        int s6 = csr[j + 12 + half], s7 = csr[j + 14 + half];
        uint2 v0 = H2[(size_t)s0 * 32 + col];
        uint2 v1 = H2[(size_t)s1 * 32 + col];
        uint2 v2 = H2[(size_t)s2 * 32 + col];
        uint2 v3 = H2[(size_t)s3 * 32 + col];
        uint2 v4 = H2[(size_t)s4 * 32 + col];
        uint2 v5 = H2[(size_t)s5 * 32 + col];
        uint2 v6 = H2[(size_t)s6 * 32 + col];
        uint2 v7 = H2[(size_t)s7 * 32 + col];
        ACCUM(v0); ACCUM(v1); ACCUM(v2); ACCUM(v3);
        ACCUM(v4); ACCUM(v5); ACCUM(v6); ACCUM(v7);
    }
    if (j + 8 <= end) {
        int s0 = csr[j + half], s1 = csr[j + 2 + half];
        int s2 = csr[j + 4 + half], s3 = csr[j + 6 + half];
        uint2 v0 = H2[(size_t)s0 * 32 + col];
        uint2 v1 = H2[(size_t)s1 * 32 + col];
        uint2 v2 = H2[(size_t)s2 * 32 + col];
        uint2 v3 = H2[(size_t)s3 * 32 + col];
        ACCUM(v0); ACCUM(v1); ACCUM(v2); ACCUM(v3);
        j += 8;
    }
    if (j + 4 <= end) {
        int s0 = csr[j + half], s1 = csr[j + 2 + half];
        uint2 v0 = H2[(size_t)s0 * 32 + col];
        uint2 v1 = H2[(size_t)s1 * 32 + col];
        ACCUM(v0); ACCUM(v1);
        j += 4;
    }
    if (j + 2 <= end) {
        int s = csr[j + half];
        uint2 v = H2[(size_t)s * 32 + col];
        ACCUM(v);
        j += 2;
    }
    if (j < end && half == 0) {
        int s = csr[j];
        uint2 v = H2[(size_t)s * 32 + col];
        ACCUM(v);
    }
#undef ACCUM

    acc.x += __shfl_xor(acc.x, 32, 64);
    acc.y += __shfl_xor(acc.y, 32, 64);
    acc.z += __shfl_xor(acc.z, 32, 64);
    acc.w += __shfl_xor(acc.w, 32, 64);

    if (half == 0) {
        float di = dinv[node];
        float4 bb = b4[col];
        float4 o;
        o.x = acc.x * di + bb.x;
        o.y = acc.y * di + bb.y;
        o.z = acc.z * di + bb.z;
        o.w = acc.w * di + bb.w;
        if (relu) {
            o.x = fmaxf(o.x, 0.f); o.y = fmaxf(o.y, 0.f);
            o.z = fmaxf(o.z, 0.f); o.w = fmaxf(o.w, 0.f);
        }
        if (obf16) {
            uint2 ob;
            ob.x = pk_bf16(o.x, o.y);
            ob.y = pk_bf16(o.z, o.w);
            ((uint2*)outp)[(size_t)node * 32 + col] = ob;
        } else {
            ((float4*)outp)[(size_t)node * 32 + col] = o;
        }
    }
}

// ---------------- launch ----------------

extern "C" void kernel_launch(void* const* d_in, const int* in_sizes, int n_in,
                              void* d_out, int out_size, void* d_ws, size_t ws_size,
                              hipStream_t stream) {
    const float* x  = (const float*)d_in[0];
    const int*   ei = (const int*)d_in[1];
    const float* W1 = (const float*)d_in[2];
    const float* b1 = (const float*)d_in[3];
    const float* W2 = (const float*)d_in[4];
    const float* b2 = (const float*)d_in[5];
    float* out = (float*)d_out;

    const int* src = ei;             // edge_index[0]
    const int* dst = ei + N_EDGES;   // edge_index[1]

    char* p = (char*)d_ws;
    int*      chist  = (int*)p;              p += GRID * 256 * 4;              // 200 KB
    float*    dinv   = (float*)p;            p += ((N_NODES * 4 + 1023) & ~1023);
    int*      rowptr = (int*)p;              p += (((N_NODES + 1) * 4 + 1023) & ~1023);
    unsigned* sorted = (unsigned*)p;         p += ((N_EDGES * 4 + 1023) & ~1023);
    int*      csr    = (int*)p;              p += ((N_EDGES * 4 + 1023) & ~1023);
    uint2*    hp     = (uint2*)p;            p += (size_t)N_NODES * DIM * 2;   // bf16 gather table
    uint2*    h1b    = (uint2*)p;                                              // bf16 h1

    const int gemmBlocks = (N_NODES + 63) / 64;   // 782
    const int aggBlocks  = (N_NODES + 3) / 4;     // 12500

    // ---- bucketed CSR build: 3 dispatches, zero global atomics, no memset ----
    chunk_hist<<<GRID, 256, 0, stream>>>(dst, chist);
    sort_scatter<<<GRID, 256, 0, stream>>>(src, dst, chist, sorted);
    csr_build<<<GRID, 256, 0, stream>>>(sorted, chist, rowptr, dinv, csr);

    // ---- layer 1: hp(bf16) = (x@W1)*dinv ; aggregate+bias+relu -> h1b(bf16) ----
    gemm_xw<<<gemmBlocks, 256, 0, stream>>>(x, W1, dinv, hp, N_NODES);
    aggregate_kernel<<<aggBlocks, 256, 0, stream>>>(hp, rowptr, csr, dinv,
                                                    (const float4*)b1, (void*)h1b, 1, 1);

    // ---- layer 2: hp(bf16) = (h1b@W2)*dinv ; aggregate+bias -> out(fp32) ----
    gemm_xw_b<<<gemmBlocks, 256, 0, stream>>>(h1b, W2, dinv, hp, N_NODES);
    aggregate_kernel<<<aggBlocks, 256, 0, stream>>>(hp, rowptr, csr, dinv,
                                                    (const float4*)b2, (void*)out, 0, 0);
}